// Round 2
// baseline (1875.082 us; speedup 1.0000x reference)
//
#include <hip/hip_runtime.h>

#define N_NODES 20000
#define N_EDGES 320000
#define EPB 32            // edge-slots per attn block
#define NB  (N_EDGES/EPB) // 10000 attn blocks
#define ROWCAP 80
#define SEGCAP 48

typedef __attribute__((ext_vector_type(4))) float f32x4;
typedef __attribute__((ext_vector_type(8))) short s16x8;

__device__ __forceinline__ unsigned short f2b(float f){
  union { float f; unsigned int u; } v; v.f = f;
  unsigned int u = v.u;
  return (unsigned short)((u + 0x7fffu + ((u>>16)&1u)) >> 16);
}
__device__ __forceinline__ float b2f(unsigned short h){
  union { unsigned int u; float f; } v; v.u = ((unsigned int)h)<<16; return v.f;
}
__device__ __forceinline__ float sigm(float x){ return 1.0f/(1.0f+__expf(-x)); }
__device__ __forceinline__ float tanhfast(float x){ return 1.0f - 2.0f/(1.0f+__expf(2.0f*x)); }

// ---------------- weight prep: f32 -> bf16, build Wcat = [We | Whu | Whw] (128 x 384)
__global__ void k_prep(const float* We, const float* Whu, const float* Whw,
                       const float* Wa, const float* Wi, const float* Wh,
                       unsigned short* WcatB, unsigned short* WaB,
                       unsigned short* WiB, unsigned short* WhB){
  int i = blockIdx.x*256 + threadIdx.x;
  if (i < 49152){
    int d = i/384, k = i - d*384;
    float v = (k<128) ? We[d*128+k] : (k<256 ? Whu[d*128+k-128] : Whw[d*128+k-256]);
    WcatB[i] = f2b(v);
  } else if (i < 49152+65536){
    int j = i-49152; WaB[j] = f2b(Wa[j]);
  } else if (i < 49152+65536+49152){
    int j = i-114688; WiB[j] = f2b(Wi[j]);
  } else if (i < 212992){
    int j = i-163840; WhB[j] = f2b(Wh[j]);
  }
}

// ---------------- counting sort by src
__global__ void k_hist(const int* ei, int* cnt){
  int e = blockIdx.x*256 + threadIdx.x;
  atomicAdd(&cnt[ei[e]], 1);
}

__global__ void k_scan(const int* cnt, int* off, int* cursor){
  __shared__ int buf[1024];
  __shared__ int sbase;
  int tid = threadIdx.x;
  if (tid==0) sbase = 0;
  __syncthreads();
  for (int ch=0; ch<20; ++ch){
    int idx = ch*1024 + tid;
    int v = (idx < N_NODES) ? cnt[idx] : 0;
    buf[tid] = v;
    __syncthreads();
    for (int s=1; s<1024; s<<=1){
      int t = (tid >= s) ? buf[tid-s] : 0;
      __syncthreads();
      buf[tid] += t;
      __syncthreads();
    }
    int total = buf[1023];
    int o = sbase + buf[tid] - v;
    if (idx < N_NODES){ off[idx] = o; cursor[idx] = o; }
    __syncthreads();
    if (tid==0) sbase += total;
    __syncthreads();
  }
  if (tid==0) off[N_NODES] = sbase;
}

__global__ void k_scatter(const int* ei, int* cursor, int* sorted){
  int e = blockIdx.x*256 + threadIdx.x;
  int s = ei[e];
  int slot = atomicAdd(&cursor[s], 1);
  sorted[slot] = e;
}

// ---------------- block map: nf[b] = lower_bound(off, b*EPB)
__global__ void k_blockmap(const int* off, int* nfA){
  int b = blockIdx.x*256 + threadIdx.x;
  if (b > NB) return;
  int target = b*EPB;
  int lo = 0, hi = N_NODES;
  while (lo < hi){
    int mid = (lo + hi) >> 1;
    if (off[mid] < target) lo = mid + 1; else hi = mid;
  }
  nfA[b] = lo;
}

// ---------------- K1: messages = leaky(cat(ea, x[src], x[tgt]) @ Wcat^T)
// 64 edges x 128 out per block, K=384, 4 waves; B fragments direct from L2
__global__ __launch_bounds__(256,3) void k_messages(const float* ea, const int* ei, const float* x,
                                                    const unsigned short* WcatB,
                                                    float* msg_out, unsigned short* msgb){
  const int tid = threadIdx.x;
  const int e0 = blockIdx.x*64;
  __shared__ unsigned short A[64][392];   // 64 x 384 bf16, +8 pad (784B rows: 8-quad spread)
  {
    int i = tid>>2, q = tid&3;
    int e = e0 + i;
    int s = ei[e]; int t = ei[N_EDGES + e];
    const float* pe = ea + (size_t)e*128 + q*32;
    const float* ps = x  + (size_t)s*128 + q*32;
    const float* pt = x  + (size_t)t*128 + q*32;
    #pragma unroll
    for (int j=0;j<32;j+=4){
      float4 v = *(const float4*)(pe+j);
      A[i][q*32+j]=f2b(v.x); A[i][q*32+j+1]=f2b(v.y); A[i][q*32+j+2]=f2b(v.z); A[i][q*32+j+3]=f2b(v.w);
      v = *(const float4*)(ps+j);
      A[i][128+q*32+j]=f2b(v.x); A[i][128+q*32+j+1]=f2b(v.y); A[i][128+q*32+j+2]=f2b(v.z); A[i][128+q*32+j+3]=f2b(v.w);
      v = *(const float4*)(pt+j);
      A[i][256+q*32+j]=f2b(v.x); A[i][256+q*32+j+1]=f2b(v.y); A[i][256+q*32+j+2]=f2b(v.z); A[i][256+q*32+j+3]=f2b(v.w);
    }
  }
  __syncthreads();
  f32x4 acc[8];
  #pragma unroll
  for (int i=0;i<8;++i) acc[i] = (f32x4){0.f,0.f,0.f,0.f};
  const int w = tid>>6, l = tid&63, lr = l&15, lg = l>>4;
  for (int ks=0; ks<12; ++ks){
    s16x8 af = *(const s16x8*)&A[w*16 + lr][ks*32 + lg*8];
    #pragma unroll
    for (int nt=0; nt<8; ++nt){
      s16x8 bf = *(const s16x8*)(WcatB + ((nt*16+lr)*384 + ks*32 + lg*8));
      acc[nt] = __builtin_amdgcn_mfma_f32_16x16x32_bf16(af, bf, acc[nt], 0,0,0);
    }
  }
  #pragma unroll
  for (int nt=0;nt<8;++nt){
    #pragma unroll
    for (int j=0;j<4;++j){
      int row = e0 + w*16 + lg*4 + j;
      int col = nt*16 + lr;
      float v = acc[nt][j];
      v = (v>0.f) ? v : 0.01f*v;
      msg_out[(size_t)row*128 + col] = v;
      msgb[(size_t)row*128 + col] = f2b(v);
    }
  }
}

// ---------------- K2: node-packed segment softmax + head-collapse + scatter
// block b: nodes n with off[n] in [b*EPB, (b+1)*EPB); rows = their edges (<=80)
// 8 chunks of 16 output features; exp in regs; per-node sums + head-collapse in LDS
__global__ __launch_bounds__(256,4) void k_attn(const unsigned short* msgb, const unsigned short* WaB,
                                                const int* ei, const int* off, const int* sorted,
                                                const int* nfA, float* agg){
  __shared__ unsigned short A[ROWCAP][128];     // msg bf16, XOR-swizzled rows
  __shared__ float Psum[ROWCAP][17];            // head-collapsed prob, +1 pad
  __shared__ float SumBuf[SEGCAP][4][16];       // per-(node,head,feat) exp sums
  __shared__ int offl[64];
  __shared__ int rtgt[ROWCAP];
  __shared__ int rseg[ROWCAP];
  const int b = blockIdx.x;
  const int tid = threadIdx.x;
  const int nf0 = nfA[b], nf1 = nfA[b+1];
  const int rb = off[nf0];
  int rows = off[nf1] - rb;
  if (rows <= 0) return;                         // uniform: no barriers yet
  if (rows > ROWCAP) rows = ROWCAP;
  int nseg = nf1 - nf0; if (nseg > 63) nseg = 63;
  if (tid <= nseg) offl[tid] = off[nf0 + tid];
  {
    int c = tid & 15;
    #pragma unroll
    for (int p=0;p<5;++p){
      int i = p*16 + (tid>>4);
      int colsw = (c*8) ^ ((i&7)<<3);
      if (i < rows){
        int e = sorted[rb + i];
        *(s16x8*)&A[i][colsw] = *(const s16x8*)(msgb + (size_t)e*128 + c*8);
        if (c==0) rtgt[i] = ei[N_EDGES + e];
      } else {
        *(s16x8*)&A[i][colsw] = (s16x8){0,0,0,0,0,0,0,0};
        if (c==0) rtgt[i] = 0;
      }
      if (c==1) rseg[i] = 0;
    }
  }
  __syncthreads();
  if (tid < rows){
    int gr = rb + tid, s = 0;
    while (offl[s+1] <= gr) ++s;
    rseg[tid] = (s < SEGCAP) ? s : (SEGCAP-1);
  }
  for (int i = tid; i < SEGCAP*64; i += 256) ((float*)SumBuf)[i] = 0.f;
  for (int i = tid; i < ROWCAP*17; i += 256) ((float*)Psum)[i] = 0.f;
  __syncthreads();
  const int w = tid>>6, l = tid&63, lr = l&15, lg = l>>4;
  const int R = (rows + 15) >> 4;
  for (int ch = 0; ch < 8; ++ch){
    // B fragments: W_attn row = w*128 + ch*16 + lr
    s16x8 bf[4];
    #pragma unroll
    for (int ks=0;ks<4;++ks)
      bf[ks] = *(const s16x8*)(WaB + ((size_t)(w*128 + ch*16 + lr)*128 + ks*32 + lg*8));
    float ev[5][4];
    #pragma unroll
    for (int rt=0; rt<5; ++rt){
      if (rt < R){
        f32x4 acc = (f32x4){0.f,0.f,0.f,0.f};
        #pragma unroll
        for (int ks=0;ks<4;++ks){
          int row = rt*16 + lr;
          s16x8 af = *(const s16x8*)&A[row][(ks*32 + lg*8) ^ ((row&7)<<3)];
          acc = __builtin_amdgcn_mfma_f32_16x16x32_bf16(af, bf[ks], acc, 0,0,0);
        }
        int rbase = rt*16 + lg*4;
        #pragma unroll
        for (int j=0;j<4;++j)
          ev[rt][j] = (rbase + j < rows) ? __expf(acc[j]) : 0.f;
        int s0 = rseg[rbase], s3 = rseg[rbase+3];
        if (s0 == s3){
          atomicAdd(&SumBuf[s0][w][lr], ev[rt][0]+ev[rt][1]+ev[rt][2]+ev[rt][3]);
        } else {
          #pragma unroll
          for (int j=0;j<4;++j) atomicAdd(&SumBuf[rseg[rbase+j]][w][lr], ev[rt][j]);
        }
      } else {
        #pragma unroll
        for (int j=0;j<4;++j) ev[rt][j] = 0.f;
      }
    }
    __syncthreads();
    #pragma unroll
    for (int rt=0; rt<5; ++rt){
      if (rt < R){
        int rbase = rt*16 + lg*4;
        #pragma unroll
        for (int j=0;j<4;++j){
          float e = ev[rt][j];
          if (e != 0.f){
            float s = SumBuf[rseg[rbase+j]][w][lr];
            atomicAdd(&Psum[rbase+j][lr], e * __builtin_amdgcn_rcpf(s));
          }
        }
      }
    }
    __syncthreads();
    for (int idx = tid; idx < rows*16; idx += 256){
      int row = idx>>4, dd = idx&15;
      int d = ch*16 + dd;
      float v = Psum[row][dd];
      float m = b2f(A[row][d ^ ((row&7)<<3)]);
      atomicAdd(&agg[(size_t)rtgt[row]*128 + d], 0.25f*v*m);
    }
    __syncthreads();
    if (ch < 7){
      for (int i = tid; i < SEGCAP*64; i += 256) ((float*)SumBuf)[i] = 0.f;
      for (int i = tid; i < ROWCAP*17; i += 256) ((float*)Psum)[i] = 0.f;
      __syncthreads();
    }
  }
}

// ---------------- K3: GRU cell, 64 nodes per block
__global__ __launch_bounds__(256,2) void k_gru(const float* x, const float* agg,
                                               const unsigned short* WiB, const unsigned short* WhB,
                                               const float* bih, const float* bhh, float* emb){
  const int base = blockIdx.x*64;
  __shared__ unsigned short Ax[64][136];
  __shared__ unsigned short Ag[64][136];
  const int tid = threadIdx.x;
  {
    int i = tid>>2, q = tid&3;
    int node = base + i;
    #pragma unroll
    for (int j=0;j<32;j+=4){
      float4 vx = {0,0,0,0}, vg = {0,0,0,0};
      if (node < N_NODES){
        vx = *(const float4*)(x   + (size_t)node*128 + q*32 + j);
        vg = *(const float4*)(agg + (size_t)node*128 + q*32 + j);
      }
      Ax[i][q*32+j]=f2b(vx.x); Ax[i][q*32+j+1]=f2b(vx.y); Ax[i][q*32+j+2]=f2b(vx.z); Ax[i][q*32+j+3]=f2b(vx.w);
      Ag[i][q*32+j]=f2b(vg.x); Ag[i][q*32+j+1]=f2b(vg.y); Ag[i][q*32+j+2]=f2b(vg.z); Ag[i][q*32+j+3]=f2b(vg.w);
    }
  }
  __syncthreads();
  const int w = tid>>6, l = tid&63, lr = l&15, lg = l>>4;
  float rr[8][4], zz[8][4];
  #pragma unroll
  for (int c=0;c<3;++c){
    f32x4 aI[8], aH[8];
    #pragma unroll
    for (int i=0;i<8;++i){ aI[i]=(f32x4){0.f,0.f,0.f,0.f}; aH[i]=(f32x4){0.f,0.f,0.f,0.f}; }
    #pragma unroll
    for (int ks=0;ks<4;++ks){
      s16x8 ax = *(const s16x8*)&Ax[w*16+lr][ks*32+lg*8];
      s16x8 ag = *(const s16x8*)&Ag[w*16+lr][ks*32+lg*8];
      #pragma unroll
      for (int nt=0;nt<8;++nt){
        s16x8 bI = *(const s16x8*)(WiB + ((c*128 + nt*16 + lr)*128 + ks*32 + lg*8));
        s16x8 bH = *(const s16x8*)(WhB + ((c*128 + nt*16 + lr)*128 + ks*32 + lg*8));
        aI[nt] = __builtin_amdgcn_mfma_f32_16x16x32_bf16(ax, bI, aI[nt], 0,0,0);
        aH[nt] = __builtin_amdgcn_mfma_f32_16x16x32_bf16(ag, bH, aH[nt], 0,0,0);
      }
    }
    #pragma unroll
    for (int nt=0;nt<8;++nt){
      float bI = bih[c*128 + nt*16 + lr];
      float bH = bhh[c*128 + nt*16 + lr];
      #pragma unroll
      for (int j=0;j<4;++j){
        float gi = aI[nt][j] + bI;
        float gh = aH[nt][j] + bH;
        if (c==0){
          rr[nt][j] = sigm(gi + gh);
        } else if (c==1){
          zz[nt][j] = sigm(gi + gh);
        } else {
          float nn = tanhfast(gi + rr[nt][j]*gh);
          int node = base + w*16 + lg*4 + j;
          int d = nt*16 + lr;
          if (node < N_NODES){
            float a = agg[(size_t)node*128 + d];
            float z = zz[nt][j];
            emb[(size_t)node*128 + d] = (1.0f - z)*nn + z*a;
          }
        }
      }
    }
  }
}

extern "C" void kernel_launch(void* const* d_in, const int* in_sizes, int n_in,
                              void* d_out, int out_size, void* d_ws, size_t ws_size,
                              hipStream_t stream){
  (void)in_sizes; (void)n_in; (void)out_size;
  const float* x    = (const float*)d_in[0];
  const int*   ei   = (const int*)d_in[1];
  const float* ea   = (const float*)d_in[2];
  const float* We   = (const float*)d_in[4];
  const float* Whu  = (const float*)d_in[5];
  const float* Whw  = (const float*)d_in[6];
  const float* Wa   = (const float*)d_in[7];
  const float* Wi   = (const float*)d_in[8];
  const float* Wh   = (const float*)d_in[9];
  const float* bih  = (const float*)d_in[10];
  const float* bhh  = (const float*)d_in[11];
  float* out = (float*)d_out;
  float* emb = out;
  float* msg = out + (size_t)N_NODES*128;

  if (ws_size < 94200000) return;
  char* ws = (char*)d_ws;
  unsigned short* msgb   = (unsigned short*)(ws);                 // 81,920,000
  float*          agg    = (float*)(ws + 81920000);               // 10,240,000
  unsigned short* WcatB  = (unsigned short*)(ws + 92160000);      //     98,304
  unsigned short* WaB    = (unsigned short*)(ws + 92258304);      //    131,072
  unsigned short* WiB    = (unsigned short*)(ws + 92389376);      //     98,304
  unsigned short* WhB    = (unsigned short*)(ws + 92487680);      //     98,304
  int*            cnt    = (int*)(ws + 92585984);                 //     80,000
  int*            off    = (int*)(ws + 92665984);                 //     80,016
  int*            cursor = (int*)(ws + 92746000);                 //     80,000
  int*            sorted = (int*)(ws + 92826000);                 //  1,280,000
  int*            nfA    = (int*)(ws + 94106000);                 //     40,004

  hipMemsetAsync(agg, 0, (size_t)N_NODES*128*4, stream);
  hipMemsetAsync(cnt, 0, (size_t)N_NODES*4, stream);
  k_prep<<<832,256,0,stream>>>(We,Whu,Whw,Wa,Wi,Wh,WcatB,WaB,WiB,WhB);
  k_hist<<<1250,256,0,stream>>>(ei, cnt);
  k_scan<<<1,1024,0,stream>>>(cnt, off, cursor);
  k_blockmap<<<40,256,0,stream>>>(off, nfA);
  k_scatter<<<1250,256,0,stream>>>(ei, cursor, sorted);
  k_messages<<<5000,256,0,stream>>>(ea, ei, x, WcatB, msg, msgb);
  k_attn<<<NB,256,0,stream>>>(msgb, WaB, ei, off, sorted, nfA, agg);
  k_gru<<<313,256,0,stream>>>(x, agg, WiB, WhB, bih, bhh, emb);
}

// Round 3
// 640.246 us; speedup vs baseline: 2.9287x; 2.9287x over previous
//
#include <hip/hip_runtime.h>

#define N_NODES 20000
#define N_EDGES 320000

typedef __attribute__((ext_vector_type(4))) float f32x4;
typedef __attribute__((ext_vector_type(8))) short s16x8;

__device__ __forceinline__ unsigned short f2b(float f){
  union { float f; unsigned int u; } v; v.f = f;
  unsigned int u = v.u;
  return (unsigned short)((u + 0x7fffu + ((u>>16)&1u)) >> 16);
}
__device__ __forceinline__ float b2f(unsigned short h){
  union { unsigned int u; float f; } v; v.u = ((unsigned int)h)<<16; return v.f;
}
__device__ __forceinline__ float sigm(float x){ return 1.0f/(1.0f+__expf(-x)); }
__device__ __forceinline__ float tanhfast(float x){ return 1.0f - 2.0f/(1.0f+__expf(2.0f*x)); }

// ---------------- weight prep: f32 -> bf16, build Wcat = [We | Whu | Whw] (128 x 384)
__global__ void k_prep(const float* We, const float* Whu, const float* Whw,
                       const float* Wa, const float* Wi, const float* Wh,
                       unsigned short* WcatB, unsigned short* WaB,
                       unsigned short* WiB, unsigned short* WhB){
  int i = blockIdx.x*256 + threadIdx.x;
  if (i < 49152){
    int d = i/384, k = i - d*384;
    float v = (k<128) ? We[d*128+k] : (k<256 ? Whu[d*128+k-128] : Whw[d*128+k-256]);
    WcatB[i] = f2b(v);
  } else if (i < 49152+65536){
    int j = i-49152; WaB[j] = f2b(Wa[j]);
  } else if (i < 49152+65536+49152){
    int j = i-114688; WiB[j] = f2b(Wi[j]);
  } else if (i < 212992){
    int j = i-163840; WhB[j] = f2b(Wh[j]);
  }
}

// ---------------- counting sort by src
__global__ void k_hist(const int* ei, int* cnt){
  int e = blockIdx.x*256 + threadIdx.x;
  atomicAdd(&cnt[ei[e]], 1);
}

__global__ void k_scan(const int* cnt, int* off, int* cursor){
  __shared__ int buf[1024];
  __shared__ int sbase;
  int tid = threadIdx.x;
  if (tid==0) sbase = 0;
  __syncthreads();
  for (int ch=0; ch<20; ++ch){
    int idx = ch*1024 + tid;
    int v = (idx < N_NODES) ? cnt[idx] : 0;
    buf[tid] = v;
    __syncthreads();
    for (int s=1; s<1024; s<<=1){
      int t = (tid >= s) ? buf[tid-s] : 0;
      __syncthreads();
      buf[tid] += t;
      __syncthreads();
    }
    int total = buf[1023];
    int o = sbase + buf[tid] - v;
    if (idx < N_NODES){ off[idx] = o; cursor[idx] = o; }
    __syncthreads();
    if (tid==0) sbase += total;
    __syncthreads();
  }
  if (tid==0) off[N_NODES] = sbase;
}

__global__ void k_scatter(const int* ei, int* cursor, int* sorted){
  int e = blockIdx.x*256 + threadIdx.x;
  int s = ei[e];
  int slot = atomicAdd(&cursor[s], 1);
  sorted[slot] = e;
}

// ---------------- K1: messages = leaky(cat(ea, x[src], x[tgt]) @ Wcat^T)
// 64 edges x 128 out per block, K=384, 4 waves; B staged in LDS, 64-wide K chunks
__global__ __launch_bounds__(256,2) void k_messages(const float* ea, const int* ei, const float* x,
                                                    const unsigned short* WcatB,
                                                    float* msg_out, unsigned short* msgb){
  const int tid = threadIdx.x;
  const int e0 = blockIdx.x*64;
  __shared__ unsigned short A[64][392];   // 64 x 384 bf16, +8 pad
  __shared__ unsigned short B[128][72];   // 128 x 64 bf16 chunk, +8 pad
  {
    int i = tid>>2, q = tid&3;
    int e = e0 + i;
    int s = ei[e]; int t = ei[N_EDGES + e];
    const float* pe = ea + (size_t)e*128 + q*32;
    const float* ps = x  + (size_t)s*128 + q*32;
    const float* pt = x  + (size_t)t*128 + q*32;
    #pragma unroll
    for (int j=0;j<32;j+=4){
      float4 v = *(const float4*)(pe+j);
      A[i][q*32+j]=f2b(v.x); A[i][q*32+j+1]=f2b(v.y); A[i][q*32+j+2]=f2b(v.z); A[i][q*32+j+3]=f2b(v.w);
      v = *(const float4*)(ps+j);
      A[i][128+q*32+j]=f2b(v.x); A[i][128+q*32+j+1]=f2b(v.y); A[i][128+q*32+j+2]=f2b(v.z); A[i][128+q*32+j+3]=f2b(v.w);
      v = *(const float4*)(pt+j);
      A[i][256+q*32+j]=f2b(v.x); A[i][256+q*32+j+1]=f2b(v.y); A[i][256+q*32+j+2]=f2b(v.z); A[i][256+q*32+j+3]=f2b(v.w);
    }
  }
  f32x4 acc[8];
  #pragma unroll
  for (int i=0;i<8;++i) acc[i] = (f32x4){0.f,0.f,0.f,0.f};
  const int w = tid>>6, l = tid&63, lr = l&15, lg = l>>4;
  for (int ks2=0; ks2<6; ++ks2){
    __syncthreads();
    {
      int nrow = tid>>1, c = tid&1;
      const s16x8* src = (const s16x8*)(WcatB + nrow*384 + ks2*64 + c*32);
      s16x8 v0=src[0], v1=src[1], v2=src[2], v3=src[3];
      *(s16x8*)&B[nrow][c*32]    = v0;
      *(s16x8*)&B[nrow][c*32+8]  = v1;
      *(s16x8*)&B[nrow][c*32+16] = v2;
      *(s16x8*)&B[nrow][c*32+24] = v3;
    }
    __syncthreads();
    #pragma unroll
    for (int kk=0;kk<2;++kk){
      int ks = ks2*2 + kk;
      s16x8 af = *(const s16x8*)&A[w*16 + lr][ks*32 + lg*8];
      #pragma unroll
      for (int nt=0; nt<8; ++nt){
        s16x8 bf = *(const s16x8*)&B[nt*16 + lr][kk*32 + lg*8];
        acc[nt] = __builtin_amdgcn_mfma_f32_16x16x32_bf16(af, bf, acc[nt], 0,0,0);
      }
    }
  }
  #pragma unroll
  for (int nt=0;nt<8;++nt){
    #pragma unroll
    for (int j=0;j<4;++j){
      int row = e0 + w*16 + lg*4 + j;
      int col = nt*16 + lr;
      float v = acc[nt][j];
      v = (v>0.f) ? v : 0.01f*v;
      msg_out[(size_t)row*128 + col] = v;
      msgb[(size_t)row*128 + col] = f2b(v);
    }
  }
}

// ---------------- K2: per-src-node segment softmax + in-register head-collapse
// one block per node; wave w owns features [w*32, w*32+32) for ALL 4 heads
__global__ __launch_bounds__(256,3) void k_attn(const unsigned short* msgb, const unsigned short* WaB,
                                                const int* ei, const int* off, const int* sorted,
                                                float* agg){
  const int n = blockIdx.x;
  const int o0 = off[n];
  int deg = off[n+1] - o0;
  if (deg <= 0) return;
  int degc = deg < 48 ? deg : 48;
  __shared__ unsigned short A[48][128];   // msg bf16, 8-elem-group XOR swizzle per row
  __shared__ int rtgt[48];
  const int tid = threadIdx.x;
  {
    int c = tid & 15;
    #pragma unroll
    for (int p=0;p<3;++p){
      int i = p*16 + (tid>>4);
      int colsw = (c*8) ^ ((i&7)<<3);
      if (i < degc){
        int e = sorted[o0 + i];
        *(s16x8*)&A[i][colsw] = *(const s16x8*)(msgb + (size_t)e*128 + c*8);
        if (c==0) rtgt[i] = ei[N_EDGES + e];
      } else {
        *(s16x8*)&A[i][colsw] = (s16x8){0,0,0,0,0,0,0,0};
        if (c==0) rtgt[i] = 0;
      }
    }
  }
  __syncthreads();
  const int w = tid>>6, l = tid&63, lr = l&15, lg = l>>4;
  const int R = (degc + 15) >> 4;
  unsigned int evp[4][2][3][2];           // exp(logit) packed bf16 pairs
  float ssum[4][2];
  #pragma unroll
  for (int h=0;h<4;++h)
    #pragma unroll
    for (int t=0;t<2;++t) ssum[h][t] = 0.f;
  #pragma unroll
  for (int h=0;h<4;++h){
    s16x8 bw[2][4];
    #pragma unroll
    for (int t=0;t<2;++t)
      #pragma unroll
      for (int ks=0;ks<4;++ks)
        bw[t][ks] = *(const s16x8*)(WaB + ((size_t)(h*128 + w*32 + t*16 + lr)*128 + ks*32 + lg*8));
    #pragma unroll
    for (int t=0;t<2;++t){
      #pragma unroll
      for (int rt=0;rt<3;++rt){
        float e0v=0.f,e1v=0.f,e2v=0.f,e3v=0.f;
        if (rt < R){
          f32x4 acc = (f32x4){0.f,0.f,0.f,0.f};
          #pragma unroll
          for (int ks=0;ks<4;++ks){
            int row = rt*16 + lr;
            s16x8 af = *(const s16x8*)&A[row][(ks*32 + lg*8) ^ ((row&7)<<3)];
            acc = __builtin_amdgcn_mfma_f32_16x16x32_bf16(af, bw[t][ks], acc, 0,0,0);
          }
          int rbase = rt*16 + lg*4;
          e0v = (rbase+0 < degc) ? __expf(acc[0]) : 0.f;
          e1v = (rbase+1 < degc) ? __expf(acc[1]) : 0.f;
          e2v = (rbase+2 < degc) ? __expf(acc[2]) : 0.f;
          e3v = (rbase+3 < degc) ? __expf(acc[3]) : 0.f;
          ssum[h][t] += (e0v+e1v)+(e2v+e3v);
        }
        evp[h][t][rt][0] = ((unsigned)f2b(e1v)<<16) | f2b(e0v);
        evp[h][t][rt][1] = ((unsigned)f2b(e3v)<<16) | f2b(e2v);
      }
    }
  }
  float inv[4][2];
  #pragma unroll
  for (int h=0;h<4;++h)
    #pragma unroll
    for (int t=0;t<2;++t){
      float s = ssum[h][t];
      s += __shfl_xor(s, 16, 64);
      s += __shfl_xor(s, 32, 64);
      inv[h][t] = 1.0f / s;
    }
  #pragma unroll
  for (int t=0;t<2;++t){
    #pragma unroll
    for (int rt=0;rt<3;++rt){
      if (rt < R){
        #pragma unroll
        for (int j=0;j<4;++j){
          int row = rt*16 + lg*4 + j;
          if (row < degc){
            float p = 0.f;
            #pragma unroll
            for (int h=0;h<4;++h){
              unsigned int pk = evp[h][t][rt][j>>1];
              unsigned short bits = (j&1) ? (unsigned short)(pk>>16) : (unsigned short)(pk&0xffffu);
              p += b2f(bits) * inv[h][t];
            }
            int d = w*32 + t*16 + lr;
            float m = b2f(A[row][d ^ ((row&7)<<3)]);
            atomicAdd(&agg[(size_t)rtgt[row]*128 + d], 0.25f*p*m);
          }
        }
      }
    }
  }
}

// ---------------- K3: GRU cell, 64 nodes per block
__global__ __launch_bounds__(256,2) void k_gru(const float* x, const float* agg,
                                               const unsigned short* WiB, const unsigned short* WhB,
                                               const float* bih, const float* bhh, float* emb){
  const int base = blockIdx.x*64;
  __shared__ unsigned short Ax[64][136];
  __shared__ unsigned short Ag[64][136];
  const int tid = threadIdx.x;
  {
    int i = tid>>2, q = tid&3;
    int node = base + i;
    #pragma unroll
    for (int j=0;j<32;j+=4){
      float4 vx = {0,0,0,0}, vg = {0,0,0,0};
      if (node < N_NODES){
        vx = *(const float4*)(x   + (size_t)node*128 + q*32 + j);
        vg = *(const float4*)(agg + (size_t)node*128 + q*32 + j);
      }
      Ax[i][q*32+j]=f2b(vx.x); Ax[i][q*32+j+1]=f2b(vx.y); Ax[i][q*32+j+2]=f2b(vx.z); Ax[i][q*32+j+3]=f2b(vx.w);
      Ag[i][q*32+j]=f2b(vg.x); Ag[i][q*32+j+1]=f2b(vg.y); Ag[i][q*32+j+2]=f2b(vg.z); Ag[i][q*32+j+3]=f2b(vg.w);
    }
  }
  __syncthreads();
  const int w = tid>>6, l = tid&63, lr = l&15, lg = l>>4;
  float rr[8][4], zz[8][4];
  #pragma unroll
  for (int c=0;c<3;++c){
    f32x4 aI[8], aH[8];
    #pragma unroll
    for (int i=0;i<8;++i){ aI[i]=(f32x4){0.f,0.f,0.f,0.f}; aH[i]=(f32x4){0.f,0.f,0.f,0.f}; }
    #pragma unroll
    for (int ks=0;ks<4;++ks){
      s16x8 ax = *(const s16x8*)&Ax[w*16+lr][ks*32+lg*8];
      s16x8 ag = *(const s16x8*)&Ag[w*16+lr][ks*32+lg*8];
      #pragma unroll
      for (int nt=0;nt<8;++nt){
        s16x8 bI = *(const s16x8*)(WiB + ((c*128 + nt*16 + lr)*128 + ks*32 + lg*8));
        s16x8 bH = *(const s16x8*)(WhB + ((c*128 + nt*16 + lr)*128 + ks*32 + lg*8));
        aI[nt] = __builtin_amdgcn_mfma_f32_16x16x32_bf16(ax, bI, aI[nt], 0,0,0);
        aH[nt] = __builtin_amdgcn_mfma_f32_16x16x32_bf16(ag, bH, aH[nt], 0,0,0);
      }
    }
    #pragma unroll
    for (int nt=0;nt<8;++nt){
      float bI = bih[c*128 + nt*16 + lr];
      float bH = bhh[c*128 + nt*16 + lr];
      #pragma unroll
      for (int j=0;j<4;++j){
        float gi = aI[nt][j] + bI;
        float gh = aH[nt][j] + bH;
        if (c==0){
          rr[nt][j] = sigm(gi + gh);
        } else if (c==1){
          zz[nt][j] = sigm(gi + gh);
        } else {
          float nn = tanhfast(gi + rr[nt][j]*gh);
          int node = base + w*16 + lg*4 + j;
          int d = nt*16 + lr;
          if (node < N_NODES){
            float a = agg[(size_t)node*128 + d];
            float z = zz[nt][j];
            emb[(size_t)node*128 + d] = (1.0f - z)*nn + z*a;
          }
        }
      }
    }
  }
}

extern "C" void kernel_launch(void* const* d_in, const int* in_sizes, int n_in,
                              void* d_out, int out_size, void* d_ws, size_t ws_size,
                              hipStream_t stream){
  (void)in_sizes; (void)n_in; (void)out_size;
  const float* x    = (const float*)d_in[0];
  const int*   ei   = (const int*)d_in[1];
  const float* ea   = (const float*)d_in[2];
  const float* We   = (const float*)d_in[4];
  const float* Whu  = (const float*)d_in[5];
  const float* Whw  = (const float*)d_in[6];
  const float* Wa   = (const float*)d_in[7];
  const float* Wi   = (const float*)d_in[8];
  const float* Wh   = (const float*)d_in[9];
  const float* bih  = (const float*)d_in[10];
  const float* bhh  = (const float*)d_in[11];
  float* out = (float*)d_out;
  float* emb = out;
  float* msg = out + (size_t)N_NODES*128;

  if (ws_size < 94200000) return;
  char* ws = (char*)d_ws;
  unsigned short* msgb   = (unsigned short*)(ws);                 // 81,920,000
  float*          agg    = (float*)(ws + 81920000);               // 10,240,000
  unsigned short* WcatB  = (unsigned short*)(ws + 92160000);      //     98,304
  unsigned short* WaB    = (unsigned short*)(ws + 92258304);      //    131,072
  unsigned short* WiB    = (unsigned short*)(ws + 92389376);      //     98,304
  unsigned short* WhB    = (unsigned short*)(ws + 92487680);      //     98,304
  int*            cnt    = (int*)(ws + 92585984);                 //     80,000
  int*            off    = (int*)(ws + 92665984);                 //     80,016
  int*            cursor = (int*)(ws + 92746000);                 //     80,000
  int*            sorted = (int*)(ws + 92826000);                 //  1,280,000

  hipMemsetAsync(agg, 0, (size_t)N_NODES*128*4, stream);
  hipMemsetAsync(cnt, 0, (size_t)N_NODES*4, stream);
  k_prep<<<832,256,0,stream>>>(We,Whu,Whw,Wa,Wi,Wh,WcatB,WaB,WiB,WhB);
  k_hist<<<1250,256,0,stream>>>(ei, cnt);
  k_scan<<<1,1024,0,stream>>>(cnt, off, cursor);
  k_scatter<<<1250,256,0,stream>>>(ei, cursor, sorted);
  k_messages<<<5000,256,0,stream>>>(ea, ei, x, WcatB, msg, msgb);
  k_attn<<<N_NODES,256,0,stream>>>(msgb, WaB, ei, off, sorted, agg);
  k_gru<<<313,256,0,stream>>>(x, agg, WiB, WhB, bih, bhh, emb);
}

// Round 4
// 614.976 us; speedup vs baseline: 3.0490x; 1.0411x over previous
//
#include <hip/hip_runtime.h>

#define N_NODES 20000
#define N_EDGES 320000
#define NPB 8                 // nodes per attn block
#define NBATT (N_NODES/NPB)   // 2500 attn blocks

typedef __attribute__((ext_vector_type(4))) float f32x4;
typedef __attribute__((ext_vector_type(8))) short s16x8;

__device__ __forceinline__ unsigned short f2b(float f){
  union { float f; unsigned int u; } v; v.f = f;
  unsigned int u = v.u;
  return (unsigned short)((u + 0x7fffu + ((u>>16)&1u)) >> 16);
}
__device__ __forceinline__ unsigned int pk2(float a, float b){
  return ((unsigned int)f2b(b)<<16) | (unsigned int)f2b(a);
}
__device__ __forceinline__ float b2f(unsigned short h){
  union { unsigned int u; float f; } v; v.u = ((unsigned int)h)<<16; return v.f;
}
__device__ __forceinline__ float sigm(float x){ return 1.0f/(1.0f+__expf(-x)); }
__device__ __forceinline__ float tanhfast(float x){ return 1.0f - 2.0f/(1.0f+__expf(2.0f*x)); }

// ---------------- weight prep: f32 -> bf16, build Wcat = [We | Whu | Whw] (128 x 384)
__global__ void k_prep(const float* We, const float* Whu, const float* Whw,
                       const float* Wa, const float* Wi, const float* Wh,
                       unsigned short* WcatB, unsigned short* WaB,
                       unsigned short* WiB, unsigned short* WhB){
  int i = blockIdx.x*256 + threadIdx.x;
  if (i < 49152){
    int d = i/384, k = i - d*384;
    float v = (k<128) ? We[d*128+k] : (k<256 ? Whu[d*128+k-128] : Whw[d*128+k-256]);
    WcatB[i] = f2b(v);
  } else if (i < 49152+65536){
    int j = i-49152; WaB[j] = f2b(Wa[j]);
  } else if (i < 49152+65536+49152){
    int j = i-114688; WiB[j] = f2b(Wi[j]);
  } else if (i < 212992){
    int j = i-163840; WhB[j] = f2b(Wh[j]);
  }
}

// ---------------- counting sort by src
__global__ void k_hist(const int* ei, int* cnt){
  int e = blockIdx.x*256 + threadIdx.x;
  atomicAdd(&cnt[ei[e]], 1);
}

__global__ void k_scan(const int* cnt, int* off, int* cursor){
  __shared__ int buf[1024];
  __shared__ int sbase;
  int tid = threadIdx.x;
  if (tid==0) sbase = 0;
  __syncthreads();
  for (int ch=0; ch<20; ++ch){
    int idx = ch*1024 + tid;
    int v = (idx < N_NODES) ? cnt[idx] : 0;
    buf[tid] = v;
    __syncthreads();
    for (int s=1; s<1024; s<<=1){
      int t = (tid >= s) ? buf[tid-s] : 0;
      __syncthreads();
      buf[tid] += t;
      __syncthreads();
    }
    int total = buf[1023];
    int o = sbase + buf[tid] - v;
    if (idx < N_NODES){ off[idx] = o; cursor[idx] = o; }
    __syncthreads();
    if (tid==0) sbase += total;
    __syncthreads();
  }
  if (tid==0) off[N_NODES] = sbase;
}

__global__ void k_scatter(const int* ei, int* cursor, int* sorted){
  int e = blockIdx.x*256 + threadIdx.x;
  int s = ei[e];
  int slot = atomicAdd(&cursor[s], 1);
  sorted[slot] = e;
}

// ---------------- K1: messages = leaky(cat(ea, x[src], x[tgt]) @ Wcat^T)
// 64 edges x 128 out per block; Wcat fragments register-resident per wave
__global__ __launch_bounds__(256,3) void k_messages(const float* ea, const int* ei, const float* x,
                                                    const unsigned short* WcatB,
                                                    float* msg_out, unsigned short* msgb){
  const int tid = threadIdx.x;
  const int e0 = blockIdx.x*64;
  __shared__ unsigned short A[64][392];   // 64 x 384 bf16, +8 pad
  const int w = tid>>6, l = tid&63, lr = l&15, lg = l>>4;
  // B fragments: wave w owns output cols [w*32, w*32+32)
  s16x8 bfr[2][12];
  #pragma unroll
  for (int nt2=0; nt2<2; ++nt2){
    int colr = w*32 + nt2*16 + lr;
    #pragma unroll
    for (int ks=0; ks<12; ++ks)
      bfr[nt2][ks] = *(const s16x8*)(WcatB + colr*384 + ks*32 + lg*8);
  }
  {
    int i = tid>>2, q = tid&3;
    int e = e0 + i;
    int s = ei[e]; int t = ei[N_EDGES + e];
    const float* pe = ea + (size_t)e*128 + q*32;
    const float* ps = x  + (size_t)s*128 + q*32;
    const float* pt = x  + (size_t)t*128 + q*32;
    #pragma unroll
    for (int j=0;j<32;j+=8){
      float4 v0 = *(const float4*)(pe+j), v1 = *(const float4*)(pe+j+4);
      *(uint4*)&A[i][q*32+j] = (uint4){pk2(v0.x,v0.y),pk2(v0.z,v0.w),pk2(v1.x,v1.y),pk2(v1.z,v1.w)};
      v0 = *(const float4*)(ps+j); v1 = *(const float4*)(ps+j+4);
      *(uint4*)&A[i][128+q*32+j] = (uint4){pk2(v0.x,v0.y),pk2(v0.z,v0.w),pk2(v1.x,v1.y),pk2(v1.z,v1.w)};
      v0 = *(const float4*)(pt+j); v1 = *(const float4*)(pt+j+4);
      *(uint4*)&A[i][256+q*32+j] = (uint4){pk2(v0.x,v0.y),pk2(v0.z,v0.w),pk2(v1.x,v1.y),pk2(v1.z,v1.w)};
    }
  }
  __syncthreads();
  f32x4 acc[4][2];
  #pragma unroll
  for (int rt=0;rt<4;++rt)
    #pragma unroll
    for (int n2=0;n2<2;++n2) acc[rt][n2] = (f32x4){0.f,0.f,0.f,0.f};
  for (int ks=0; ks<12; ++ks){
    #pragma unroll
    for (int rt=0;rt<4;++rt){
      s16x8 af = *(const s16x8*)&A[rt*16 + lr][ks*32 + lg*8];
      acc[rt][0] = __builtin_amdgcn_mfma_f32_16x16x32_bf16(af, bfr[0][ks], acc[rt][0], 0,0,0);
      acc[rt][1] = __builtin_amdgcn_mfma_f32_16x16x32_bf16(af, bfr[1][ks], acc[rt][1], 0,0,0);
    }
  }
  #pragma unroll
  for (int rt=0;rt<4;++rt){
    #pragma unroll
    for (int n2=0;n2<2;++n2){
      int col = w*32 + n2*16 + lr;
      #pragma unroll
      for (int j=0;j<4;++j){
        int row = e0 + rt*16 + lg*4 + j;
        float v = acc[rt][n2][j];
        v = (v>0.f) ? v : 0.01f*v;
        msg_out[(size_t)row*128 + col] = v;
        msgb[(size_t)row*128 + col] = f2b(v);
      }
    }
  }
}

// ---------------- K2: 8 nodes per block; W_attn frags hoisted; A double-buffered
// wave w owns features [w*32, w*32+32) for ALL 4 heads
__global__ __launch_bounds__(256,2) void k_attn(const unsigned short* msgb, const unsigned short* WaB,
                                                const int* ei, const int* off, const int* sorted,
                                                float* agg){
  __shared__ unsigned short A[2][48][128];  // msg bf16, 8-elem-group XOR swizzle per row
  __shared__ int rtgt[2][48];
  __shared__ int offl[NPB+1];
  const int tid = threadIdx.x;
  const int n0 = blockIdx.x*NPB;
  if (tid <= NPB) offl[tid] = off[n0 + tid];
  const int w = tid>>6, l = tid&63, lr = l&15, lg = l>>4;
  // hoist W_attn fragments: 32 x s16x8 = 128 VGPR, loaded once per block
  s16x8 bw[4][2][4];
  #pragma unroll
  for (int h=0;h<4;++h)
    #pragma unroll
    for (int t=0;t<2;++t)
      #pragma unroll
      for (int ks=0;ks<4;++ks)
        bw[h][t][ks] = *(const s16x8*)(WaB + ((size_t)(h*128 + w*32 + t*16 + lr)*128 + ks*32 + lg*8));
  __syncthreads();

  const int c16 = tid & 15;
  // stage node 0 into buf 0
  {
    int rb = offl[0];
    int degc = offl[1] - rb; if (degc > 48) degc = 48;
    #pragma unroll
    for (int p=0;p<3;++p){
      int i = p*16 + (tid>>4);
      int colsw = (c16*8) ^ ((i&7)<<3);
      if (i < degc){
        int e = sorted[rb + i];
        *(s16x8*)&A[0][i][colsw] = *(const s16x8*)(msgb + (size_t)e*128 + c16*8);
        if (c16==0) rtgt[0][i] = ei[N_EDGES + e];
      } else {
        *(s16x8*)&A[0][i][colsw] = (s16x8){0,0,0,0,0,0,0,0};
        if (c16==0) rtgt[0][i] = 0;
      }
    }
  }
  __syncthreads();

  int cur = 0;
  for (int ni=0; ni<NPB; ++ni){
    // prefetch next node into the other buffer
    if (ni+1 < NPB){
      int rb = offl[ni+1];
      int degc = offl[ni+2] - rb; if (degc > 48) degc = 48;
      #pragma unroll
      for (int p=0;p<3;++p){
        int i = p*16 + (tid>>4);
        int colsw = (c16*8) ^ ((i&7)<<3);
        if (i < degc){
          int e = sorted[rb + i];
          *(s16x8*)&A[cur^1][i][colsw] = *(const s16x8*)(msgb + (size_t)e*128 + c16*8);
          if (c16==0) rtgt[cur^1][i] = ei[N_EDGES + e];
        } else {
          *(s16x8*)&A[cur^1][i][colsw] = (s16x8){0,0,0,0,0,0,0,0};
          if (c16==0) rtgt[cur^1][i] = 0;
        }
      }
    }
    // compute current node
    {
      int degc = offl[ni+1] - offl[ni]; if (degc > 48) degc = 48;
      if (degc > 0){
        const int R = (degc + 15) >> 4;
        #pragma unroll
        for (int t=0;t<2;++t){
          unsigned int evp[4][3][2];
          float ssum[4];
          #pragma unroll
          for (int h=0;h<4;++h) ssum[h] = 0.f;
          #pragma unroll
          for (int h=0;h<4;++h){
            #pragma unroll
            for (int rt=0;rt<3;++rt){
              float e0v=0.f,e1v=0.f,e2v=0.f,e3v=0.f;
              if (rt < R){
                f32x4 acc = (f32x4){0.f,0.f,0.f,0.f};
                #pragma unroll
                for (int ks=0;ks<4;++ks){
                  s16x8 af = *(const s16x8*)&A[cur][rt*16 + lr][(ks*32 + lg*8) ^ ((lr&7)<<3)];
                  acc = __builtin_amdgcn_mfma_f32_16x16x32_bf16(af, bw[h][t][ks], acc, 0,0,0);
                }
                int rbase = rt*16 + lg*4;
                e0v = (rbase+0 < degc) ? __expf(acc[0]) : 0.f;
                e1v = (rbase+1 < degc) ? __expf(acc[1]) : 0.f;
                e2v = (rbase+2 < degc) ? __expf(acc[2]) : 0.f;
                e3v = (rbase+3 < degc) ? __expf(acc[3]) : 0.f;
                ssum[h] += (e0v+e1v)+(e2v+e3v);
              }
              evp[h][rt][0] = pk2(e0v,e1v);
              evp[h][rt][1] = pk2(e2v,e3v);
            }
          }
          float inv[4];
          #pragma unroll
          for (int h=0;h<4;++h){
            float s = ssum[h];
            s += __shfl_xor(s, 16, 64);
            s += __shfl_xor(s, 32, 64);
            inv[h] = 1.0f / s;
          }
          #pragma unroll
          for (int rt=0;rt<3;++rt){
            if (rt < R){
              #pragma unroll
              for (int j=0;j<4;++j){
                int row = rt*16 + lg*4 + j;
                if (row < degc){
                  float p = 0.f;
                  #pragma unroll
                  for (int h=0;h<4;++h){
                    unsigned int pkv = evp[h][rt][j>>1];
                    unsigned short bits = (j&1) ? (unsigned short)(pkv>>16) : (unsigned short)(pkv&0xffffu);
                    p += b2f(bits) * inv[h];
                  }
                  int d = w*32 + t*16 + lr;
                  float m = b2f(A[cur][row][d ^ ((row&7)<<3)]);
                  atomicAdd(&agg[(size_t)rtgt[cur][row]*128 + d], 0.25f*p*m);
                }
              }
            }
          }
        }
      }
    }
    __syncthreads();
    cur ^= 1;
  }
}

// ---------------- K3: GRU cell, 64 nodes per block
__global__ __launch_bounds__(256,2) void k_gru(const float* x, const float* agg,
                                               const unsigned short* WiB, const unsigned short* WhB,
                                               const float* bih, const float* bhh, float* emb){
  const int base = blockIdx.x*64;
  __shared__ unsigned short Ax[64][136];
  __shared__ unsigned short Ag[64][136];
  const int tid = threadIdx.x;
  {
    int i = tid>>2, q = tid&3;
    int node = base + i;
    #pragma unroll
    for (int j=0;j<32;j+=8){
      float4 vx0={0,0,0,0},vx1={0,0,0,0},vg0={0,0,0,0},vg1={0,0,0,0};
      if (node < N_NODES){
        vx0 = *(const float4*)(x   + (size_t)node*128 + q*32 + j);
        vx1 = *(const float4*)(x   + (size_t)node*128 + q*32 + j + 4);
        vg0 = *(const float4*)(agg + (size_t)node*128 + q*32 + j);
        vg1 = *(const float4*)(agg + (size_t)node*128 + q*32 + j + 4);
      }
      *(uint4*)&Ax[i][q*32+j] = (uint4){pk2(vx0.x,vx0.y),pk2(vx0.z,vx0.w),pk2(vx1.x,vx1.y),pk2(vx1.z,vx1.w)};
      *(uint4*)&Ag[i][q*32+j] = (uint4){pk2(vg0.x,vg0.y),pk2(vg0.z,vg0.w),pk2(vg1.x,vg1.y),pk2(vg1.z,vg1.w)};
    }
  }
  __syncthreads();
  const int w = tid>>6, l = tid&63, lr = l&15, lg = l>>4;
  float rr[8][4], zz[8][4];
  #pragma unroll
  for (int c=0;c<3;++c){
    f32x4 aI[8], aH[8];
    #pragma unroll
    for (int i=0;i<8;++i){ aI[i]=(f32x4){0.f,0.f,0.f,0.f}; aH[i]=(f32x4){0.f,0.f,0.f,0.f}; }
    #pragma unroll
    for (int ks=0;ks<4;++ks){
      s16x8 ax = *(const s16x8*)&Ax[w*16+lr][ks*32+lg*8];
      s16x8 ag = *(const s16x8*)&Ag[w*16+lr][ks*32+lg*8];
      #pragma unroll
      for (int nt=0;nt<8;++nt){
        s16x8 bI = *(const s16x8*)(WiB + ((c*128 + nt*16 + lr)*128 + ks*32 + lg*8));
        s16x8 bH = *(const s16x8*)(WhB + ((c*128 + nt*16 + lr)*128 + ks*32 + lg*8));
        aI[nt] = __builtin_amdgcn_mfma_f32_16x16x32_bf16(ax, bI, aI[nt], 0,0,0);
        aH[nt] = __builtin_amdgcn_mfma_f32_16x16x32_bf16(ag, bH, aH[nt], 0,0,0);
      }
    }
    #pragma unroll
    for (int nt=0;nt<8;++nt){
      float bI = bih[c*128 + nt*16 + lr];
      float bH = bhh[c*128 + nt*16 + lr];
      #pragma unroll
      for (int j=0;j<4;++j){
        float gi = aI[nt][j] + bI;
        float gh = aH[nt][j] + bH;
        if (c==0){
          rr[nt][j] = sigm(gi + gh);
        } else if (c==1){
          zz[nt][j] = sigm(gi + gh);
        } else {
          float nn = tanhfast(gi + rr[nt][j]*gh);
          int node = base + w*16 + lg*4 + j;
          int d = nt*16 + lr;
          if (node < N_NODES){
            float a = agg[(size_t)node*128 + d];
            float z = zz[nt][j];
            emb[(size_t)node*128 + d] = (1.0f - z)*nn + z*a;
          }
        }
      }
    }
  }
}

extern "C" void kernel_launch(void* const* d_in, const int* in_sizes, int n_in,
                              void* d_out, int out_size, void* d_ws, size_t ws_size,
                              hipStream_t stream){
  (void)in_sizes; (void)n_in; (void)out_size;
  const float* x    = (const float*)d_in[0];
  const int*   ei   = (const int*)d_in[1];
  const float* ea   = (const float*)d_in[2];
  const float* We   = (const float*)d_in[4];
  const float* Whu  = (const float*)d_in[5];
  const float* Whw  = (const float*)d_in[6];
  const float* Wa   = (const float*)d_in[7];
  const float* Wi   = (const float*)d_in[8];
  const float* Wh   = (const float*)d_in[9];
  const float* bih  = (const float*)d_in[10];
  const float* bhh  = (const float*)d_in[11];
  float* out = (float*)d_out;
  float* emb = out;
  float* msg = out + (size_t)N_NODES*128;

  if (ws_size < 94200000) return;
  char* ws = (char*)d_ws;
  unsigned short* msgb   = (unsigned short*)(ws);                 // 81,920,000
  float*          agg    = (float*)(ws + 81920000);               // 10,240,000
  unsigned short* WcatB  = (unsigned short*)(ws + 92160000);      //     98,304
  unsigned short* WaB    = (unsigned short*)(ws + 92258304);      //    131,072
  unsigned short* WiB    = (unsigned short*)(ws + 92389376);      //     98,304
  unsigned short* WhB    = (unsigned short*)(ws + 92487680);      //     98,304
  int*            cnt    = (int*)(ws + 92585984);                 //     80,000
  int*            off    = (int*)(ws + 92665984);                 //     80,016
  int*            cursor = (int*)(ws + 92746000);                 //     80,000
  int*            sorted = (int*)(ws + 92826000);                 //  1,280,000

  hipMemsetAsync(agg, 0, (size_t)N_NODES*128*4, stream);
  hipMemsetAsync(cnt, 0, (size_t)N_NODES*4, stream);
  k_prep<<<832,256,0,stream>>>(We,Whu,Whw,Wa,Wi,Wh,WcatB,WaB,WiB,WhB);
  k_hist<<<1250,256,0,stream>>>(ei, cnt);
  k_scan<<<1,1024,0,stream>>>(cnt, off, cursor);
  k_scatter<<<1250,256,0,stream>>>(ei, cursor, sorted);
  k_messages<<<5000,256,0,stream>>>(ea, ei, x, WcatB, msg, msgb);
  k_attn<<<NBATT,256,0,stream>>>(msgb, WaB, ei, off, sorted, agg);
  k_gru<<<313,256,0,stream>>>(x, agg, WiB, WhB, bih, bhh, emb);
}